// Round 6
// baseline (388.406 us; speedup 1.0000x reference)
//
#include <hip/hip_runtime.h>
#include <hip/hip_bf16.h>

#define N_NODES 50000
#define N_EDGES 800000
#define ETOT    (N_EDGES + N_NODES)
#define NB      64
#define IN_C    128
#define HID     64
#define HEADS   4
#define F1      (HEADS * HID)   /* 256 */
#define NEG     0.2f
#define SCAN_NBLK ((N_NODES + 255) / 256)   /* 196 */

typedef __attribute__((ext_vector_type(8))) short  short8v;
typedef __attribute__((ext_vector_type(4))) float  float4v;

__device__ __forceinline__ float lrelu(float x) { return x >= 0.f ? x : NEG * x; }

// round-to-nearest-even f32 -> bf16 bits
__device__ __forceinline__ unsigned short f2bf(float f) {
    unsigned u = __float_as_uint(f);
    u += 0x7FFFu + ((u >> 16) & 1u);
    return (unsigned short)(u >> 16);
}
__device__ __forceinline__ float bf2f(unsigned short h) {
    return __uint_as_float(((unsigned)h) << 16);
}

// ---------------- CSR build ----------------
__global__ void deg_kernel(const int* __restrict__ ei, int* __restrict__ deg) {
    int e = blockIdx.x * 256 + threadIdx.x;
    if (e >= ETOT) return;
    int d = (e < N_EDGES) ? ei[N_EDGES + e] : (e - N_EDGES);
    atomicAdd(&deg[d], 1);
}

// 3-phase grid-wide exclusive scan of deg[N_NODES] -> off[N_NODES+1]
__global__ void scan1_kernel(const int* __restrict__ deg, int* __restrict__ part) {
    __shared__ int sh[256];
    int t = threadIdx.x;
    int i = blockIdx.x * 256 + t;
    sh[t] = (i < N_NODES) ? deg[i] : 0;
    __syncthreads();
    #pragma unroll
    for (int o = 128; o; o >>= 1) {
        if (t < o) sh[t] += sh[t + o];
        __syncthreads();
    }
    if (t == 0) part[blockIdx.x] = sh[0];
}

__global__ void scan2_kernel(int* __restrict__ part, int* __restrict__ off) {
    __shared__ int sh[256];
    int t = threadIdx.x;
    int v = (t < SCAN_NBLK) ? part[t] : 0;
    sh[t] = v;
    __syncthreads();
    #pragma unroll
    for (int o = 1; o < 256; o <<= 1) {
        int u = (t >= o) ? sh[t - o] : 0;
        __syncthreads();
        sh[t] += u;
        __syncthreads();
    }
    if (t < SCAN_NBLK) part[t] = sh[t] - v;       // exclusive block base
    if (t == 255) off[N_NODES] = sh[255];
}

__global__ void scan3_kernel(int* __restrict__ deg, const int* __restrict__ part,
                             int* __restrict__ off) {
    __shared__ int sh[256];
    int t = threadIdx.x;
    int i = blockIdx.x * 256 + t;
    int v = (i < N_NODES) ? deg[i] : 0;
    sh[t] = v;
    __syncthreads();
    #pragma unroll
    for (int o = 1; o < 256; o <<= 1) {
        int u = (t >= o) ? sh[t - o] : 0;
        __syncthreads();
        sh[t] += u;
        __syncthreads();
    }
    if (i < N_NODES) {
        off[i] = part[blockIdx.x] + sh[t] - v;
        deg[i] = 0;                                // reuse as cursor
    }
}

__global__ void scatter_kernel(const int* __restrict__ ei, const int* __restrict__ off,
                               int* __restrict__ cursor, int* __restrict__ esrc) {
    int e = blockIdx.x * 256 + threadIdx.x;
    if (e >= ETOT) return;
    int s, d;
    if (e < N_EDGES) { s = ei[e]; d = ei[N_EDGES + e]; }
    else             { s = d = e - N_EDGES; }
    int pos = off[d] + atomicAdd(&cursor[d], 1);
    esrc[pos] = s;
}

// ---------------- W [K][256] f32 -> transposed split bf16 Wt[256][K] hi/lo ----------------
__global__ void convw_kernel(const float* __restrict__ W,
                             unsigned short* __restrict__ Wth,
                             unsigned short* __restrict__ Wtl, int K) {
    int i = blockIdx.x * 256 + threadIdx.x;
    if (i >= K * 256) return;
    int k = i >> 8, n = i & 255;
    float v = W[i];
    unsigned short h = f2bf(v);
    Wth[n * K + k] = h;
    Wtl[n * K + k] = f2bf(v - bf2f(h));
}

// ---------------- split-bf16 MFMA GEMM + fused alpha + bf16 output ----------------
// C[M,256] = A[M,K] @ W[K,256]; writes Cb (bf16) and per-node alpha_src/alpha_dst.
// Wave w owns head w's 64 columns. 3-product split: Ah*Bh + Ah*Bl + Al*Bh.
template <bool SPLIT_A>
__global__ __launch_bounds__(256) void gemm_mfma(const float* __restrict__ Af32,
                                                 const unsigned short* __restrict__ Ahg,
                                                 const unsigned short* __restrict__ Alg,
                                                 const unsigned short* __restrict__ Wth,
                                                 const unsigned short* __restrict__ Wtl,
                                                 const float* __restrict__ a_s,
                                                 const float* __restrict__ a_d,
                                                 unsigned short* __restrict__ Cb,
                                                 float* __restrict__ asrcO,
                                                 float* __restrict__ adstO,
                                                 int M, int K) {
    __shared__ unsigned short Ah[64][40], Al[64][40];    // 32 + 8 pad
    __shared__ unsigned short Bh[256][40], Bl[256][40];
    int t  = threadIdx.x;
    int m0 = blockIdx.x * 64;
    int w  = t >> 6, l = t & 63;
    int lr = l & 15, lk = (l >> 4) * 8;

    float asv[4], adv[4];
    #pragma unroll
    for (int nf = 0; nf < 4; ++nf) {
        asv[nf] = a_s[w * 64 + nf * 16 + lr];
        adv[nf] = a_d[w * 64 + nf * 16 + lr];
    }

    float4v acc[4][4];
    #pragma unroll
    for (int mf = 0; mf < 4; ++mf)
        #pragma unroll
        for (int nf = 0; nf < 4; ++nf)
            acc[mf][nf] = (float4v){0.f, 0.f, 0.f, 0.f};

    for (int k0 = 0; k0 < K; k0 += 32) {
        if (SPLIT_A) {
            #pragma unroll
            for (int p = 0; p < 2; ++p) {
                int idx = t + p * 256;
                int r = idx >> 3, c4 = (idx & 7) * 4;
                int gr = m0 + r;
                float4 v = make_float4(0.f, 0.f, 0.f, 0.f);
                if (gr < M) v = *(const float4*)&Af32[(size_t)gr * K + k0 + c4];
                ushort4 hi, lo;
                hi.x = f2bf(v.x); lo.x = f2bf(v.x - bf2f(hi.x));
                hi.y = f2bf(v.y); lo.y = f2bf(v.y - bf2f(hi.y));
                hi.z = f2bf(v.z); lo.z = f2bf(v.z - bf2f(hi.z));
                hi.w = f2bf(v.w); lo.w = f2bf(v.w - bf2f(hi.w));
                *(ushort4*)&Ah[r][c4] = hi;
                *(ushort4*)&Al[r][c4] = lo;
            }
        } else {
            int r = t >> 2, c8 = (t & 3) * 8;
            int gr = m0 + r;
            short8v zh = {0,0,0,0,0,0,0,0};
            short8v vh = zh, vl = zh;
            if (gr < M) {
                vh = *(const short8v*)&Ahg[(size_t)gr * K + k0 + c8];
                vl = *(const short8v*)&Alg[(size_t)gr * K + k0 + c8];
            }
            *(short8v*)&Ah[r][c8] = vh;
            *(short8v*)&Al[r][c8] = vl;
        }
        #pragma unroll
        for (int p = 0; p < 4; ++p) {
            int idx = t + p * 256;
            int r = idx >> 2, c8 = (idx & 3) * 8;
            short8v vh = *(const short8v*)&Wth[(size_t)r * K + k0 + c8];
            short8v vl = *(const short8v*)&Wtl[(size_t)r * K + k0 + c8];
            *(short8v*)&Bh[r][c8] = vh;
            *(short8v*)&Bl[r][c8] = vl;
        }
        __syncthreads();

        short8v a_hf[4], a_lf[4], b_hf[4], b_lf[4];
        #pragma unroll
        for (int mf = 0; mf < 4; ++mf) {
            a_hf[mf] = *(short8v*)&Ah[mf * 16 + lr][lk];
            a_lf[mf] = *(short8v*)&Al[mf * 16 + lr][lk];
        }
        #pragma unroll
        for (int nf = 0; nf < 4; ++nf) {
            b_hf[nf] = *(short8v*)&Bh[w * 64 + nf * 16 + lr][lk];
            b_lf[nf] = *(short8v*)&Bl[w * 64 + nf * 16 + lr][lk];
        }
        #pragma unroll
        for (int mf = 0; mf < 4; ++mf)
            #pragma unroll
            for (int nf = 0; nf < 4; ++nf) {
                acc[mf][nf] = __builtin_amdgcn_mfma_f32_16x16x32_bf16(a_hf[mf], b_hf[nf], acc[mf][nf], 0, 0, 0);
                acc[mf][nf] = __builtin_amdgcn_mfma_f32_16x16x32_bf16(a_hf[mf], b_lf[nf], acc[mf][nf], 0, 0, 0);
                acc[mf][nf] = __builtin_amdgcn_mfma_f32_16x16x32_bf16(a_lf[mf], b_hf[nf], acc[mf][nf], 0, 0, 0);
            }
        __syncthreads();
    }

    // ---- fused alpha: per-row dot with a_s/a_d (head w), 16-lane reduce ----
    #pragma unroll
    for (int mf = 0; mf < 4; ++mf)
        #pragma unroll
        for (int r = 0; r < 4; ++r) {
            float ps = acc[mf][0][r] * asv[0] + acc[mf][1][r] * asv[1]
                     + acc[mf][2][r] * asv[2] + acc[mf][3][r] * asv[3];
            float pd = acc[mf][0][r] * adv[0] + acc[mf][1][r] * adv[1]
                     + acc[mf][2][r] * adv[2] + acc[mf][3][r] * adv[3];
            #pragma unroll
            for (int o = 8; o; o >>= 1) {
                ps += __shfl_xor(ps, o);
                pd += __shfl_xor(pd, o);
            }
            int gr = m0 + mf * 16 + (l >> 4) * 4 + r;
            if (lr == 0 && gr < M) {
                asrcO[gr * 4 + w] = ps;
                adstO[gr * 4 + w] = pd;
            }
        }

    // ---- bf16 C write (gather source for agg) ----
    #pragma unroll
    for (int mf = 0; mf < 4; ++mf)
        #pragma unroll
        for (int nf = 0; nf < 4; ++nf)
            #pragma unroll
            for (int r = 0; r < 4; ++r) {
                int gr = m0 + mf * 16 + (l >> 4) * 4 + r;
                if (gr < M) Cb[(size_t)gr * F1 + w * 64 + nf * 16 + lr] = f2bf(acc[mf][nf][r]);
            }
}

// ---------------- fused segment softmax + aggregation (one wave per dst node) ----------------
// Lane owns channels lane*4..lane*4+3 (all in head lane>>4): ONE ushort4 gather per edge.
// LAYER 1: out = split bf16 hi/lo of relu(agg + bias); LAYER 2: f32 head-mean + bias.
template <int LAYER>
__global__ void agg_kernel(const unsigned short* __restrict__ hb,
                           const float* __restrict__ asrc,
                           const float* __restrict__ adst,
                           const int* __restrict__ off,
                           const int* __restrict__ esrc,
                           const float* __restrict__ bias,
                           float* __restrict__ outF,
                           unsigned short* __restrict__ oh,
                           unsigned short* __restrict__ ol) {
    __shared__ int   ssh[64];
    __shared__ float cf[64][4];
    int d    = blockIdx.x;
    int lane = threadIdx.x;  // 64 = 1 wave
    int w    = lane >> 4;    // this lane's head
    int e0 = off[d], e1 = off[d + 1];
    float4 ad = *(const float4*)(adst + (size_t)d * 4);
    float den = 0.f;
    float a0 = 0.f, a1 = 0.f, a2 = 0.f, a3 = 0.f;

    for (int base = e0; base < e1; base += 64) {
        int cnt = min(64, e1 - base);
        if (lane < cnt) {
            int s = esrc[base + lane];
            ssh[lane] = s;
            float4 as = *(const float4*)(asrc + (size_t)s * 4);
            cf[lane][0] = __expf(lrelu(as.x + ad.x));
            cf[lane][1] = __expf(lrelu(as.y + ad.y));
            cf[lane][2] = __expf(lrelu(as.z + ad.z));
            cf[lane][3] = __expf(lrelu(as.w + ad.w));
        }
        __syncthreads();
        #pragma unroll 4
        for (int i = 0; i < cnt; ++i) {
            int s = ssh[i];
            float c = cf[i][w];                       // LDS broadcast within head group
            ushort4 hv = *(const ushort4*)&hb[(size_t)s * F1 + lane * 4];
            den += c;
            a0 += c * bf2f(hv.x);
            a1 += c * bf2f(hv.y);
            a2 += c * bf2f(hv.z);
            a3 += c * bf2f(hv.w);
        }
        __syncthreads();
    }

    float r = 1.f / fmaxf(den, 1e-16f);
    if (LAYER == 1) {
        float v0 = fmaxf(a0 * r + bias[lane * 4 + 0], 0.f);
        float v1 = fmaxf(a1 * r + bias[lane * 4 + 1], 0.f);
        float v2 = fmaxf(a2 * r + bias[lane * 4 + 2], 0.f);
        float v3 = fmaxf(a3 * r + bias[lane * 4 + 3], 0.f);
        ushort4 hi, lo;
        hi.x = f2bf(v0); lo.x = f2bf(v0 - bf2f(hi.x));
        hi.y = f2bf(v1); lo.y = f2bf(v1 - bf2f(hi.y));
        hi.z = f2bf(v2); lo.z = f2bf(v2 - bf2f(hi.z));
        hi.w = f2bf(v3); lo.w = f2bf(v3 - bf2f(hi.w));
        *(ushort4*)&oh[(size_t)d * F1 + lane * 4] = hi;
        *(ushort4*)&ol[(size_t)d * F1 + lane * 4] = lo;
    } else {
        float v0 = a0 * r, v1 = a1 * r, v2 = a2 * r, v3 = a3 * r;
        // head-mean: lanes {L, L^16, L^32, L^48} hold same hid for heads 0..3
        v0 += __shfl_xor(v0, 16); v0 += __shfl_xor(v0, 32);
        v1 += __shfl_xor(v1, 16); v1 += __shfl_xor(v1, 32);
        v2 += __shfl_xor(v2, 16); v2 += __shfl_xor(v2, 32);
        v3 += __shfl_xor(v3, 16); v3 += __shfl_xor(v3, 32);
        if (lane < 16) {
            float4 o;
            o.x = 0.25f * v0 + bias[lane * 4 + 0];
            o.y = 0.25f * v1 + bias[lane * 4 + 1];
            o.z = 0.25f * v2 + bias[lane * 4 + 2];
            o.w = 0.25f * v3 + bias[lane * 4 + 3];
            *(float4*)&outF[(size_t)d * HID + lane * 4] = o;
        }
    }
}

// ---------------- global mean pool: one block per graph, batch is sorted ----------------
__device__ __forceinline__ int lowerb(const int* __restrict__ a, int n, int v) {
    int lo = 0, hi = n;
    while (lo < hi) { int m = (lo + hi) >> 1; if (a[m] < v) lo = m + 1; else hi = m; }
    return lo;
}

__global__ void pool2_kernel(const float* __restrict__ h2,
                             const int* __restrict__ batch,
                             float* __restrict__ pooled) {
    __shared__ float sh[4][HID];
    int b = blockIdx.x;
    int t = threadIdx.x, w = t >> 6, c = t & 63;
    int lo = lowerb(batch, N_NODES, b);
    int hi = lowerb(batch, N_NODES, b + 1);
    float s = 0.f;
    for (int n = lo + w; n < hi; n += 4) s += h2[(size_t)n * HID + c];
    sh[w][c] = s;
    __syncthreads();
    if (w == 0) {
        float tot = sh[0][c] + sh[1][c] + sh[2][c] + sh[3][c];
        pooled[b * HID + c] = tot / fmaxf((float)(hi - lo), 1.f);
    }
}

// ---------------- graph MLP ----------------
__global__ void mlp_kernel(const float* __restrict__ pooled,
                           const float* __restrict__ Wm1, const float* __restrict__ bm1,
                           const float* __restrict__ Wm2, const float* __restrict__ bm2,
                           float* __restrict__ out) {
    __shared__ float P[NB][HID];
    __shared__ float Hh[NB][HID];
    int t = threadIdx.x;
    for (int i = t; i < NB * HID; i += 256) P[i / HID][i % HID] = pooled[i];
    __syncthreads();
    for (int i = t; i < NB * HID; i += 256) {
        int b = i / HID, c = i % HID;
        float s = bm1[c];
        for (int k = 0; k < HID; ++k) s += P[b][k] * Wm1[k * HID + c];
        Hh[b][c] = fmaxf(s, 0.f);
    }
    __syncthreads();
    if (t < NB) {
        float s = bm2[0];
        for (int k = 0; k < HID; ++k) s += Hh[t][k] * Wm2[k];
        out[t] = s;
    }
}

extern "C" void kernel_launch(void* const* d_in, const int* in_sizes, int n_in,
                              void* d_out, int out_size, void* d_ws, size_t ws_size,
                              hipStream_t stream) {
    const float* x   = (const float*)d_in[0];
    const int*   ei  = (const int*)d_in[1];
    const int*   bat = (const int*)d_in[2];
    const float* W1  = (const float*)d_in[3];
    const float* as1 = (const float*)d_in[4];
    const float* ad1 = (const float*)d_in[5];
    const float* b1  = (const float*)d_in[6];
    const float* W2  = (const float*)d_in[7];
    const float* as2 = (const float*)d_in[8];
    const float* ad2 = (const float*)d_in[9];
    const float* b2  = (const float*)d_in[10];
    const float* Wm1 = (const float*)d_in[11];
    const float* bm1 = (const float*)d_in[12];
    const float* Wm2 = (const float*)d_in[13];
    const float* bm2 = (const float*)d_in[14];
    float* out = (float*)d_out;

    char* ws = (char*)d_ws;
    size_t cursor = 0;
    auto alloc = [&](size_t bytes) {
        void* p = ws + cursor;
        cursor += (bytes + 511) & ~(size_t)511;
        return p;
    };
    int*   deg    = (int*)alloc((size_t)N_NODES * 4);
    int*   off    = (int*)alloc((size_t)(N_NODES + 1) * 4);
    int*   part   = (int*)alloc((size_t)SCAN_NBLK * 4);
    int*   esrc   = (int*)alloc((size_t)ETOT * 4);
    unsigned short* bufHb = (unsigned short*)alloc((size_t)N_NODES * F1 * 2);  // gemm bf16 out
    // union region (51.2 MB): oh/ol after agg1; bufO (agg2 out) aliases oh after gemm2
    char*  U      = (char*)alloc((size_t)N_NODES * F1 * 4);
    unsigned short* oh   = (unsigned short*)U;
    unsigned short* olsp = (unsigned short*)(U + (size_t)N_NODES * F1 * 2);
    float* bufO   = (float*)U;
    float* asrc   = (float*)alloc((size_t)N_NODES * HEADS * 4);
    float* adst   = (float*)alloc((size_t)N_NODES * HEADS * 4);
    float* pooled = (float*)alloc((size_t)NB * HID * 4);
    unsigned short* W1th = (unsigned short*)alloc((size_t)256 * IN_C * 2);
    unsigned short* W1tl = (unsigned short*)alloc((size_t)256 * IN_C * 2);
    unsigned short* W2th = (unsigned short*)alloc((size_t)256 * F1 * 2);
    unsigned short* W2tl = (unsigned short*)alloc((size_t)256 * F1 * 2);

    hipMemsetAsync(deg, 0, (size_t)N_NODES * 4, stream);

    deg_kernel<<<(ETOT + 255) / 256, 256, 0, stream>>>(ei, deg);
    scan1_kernel<<<SCAN_NBLK, 256, 0, stream>>>(deg, part);
    scan2_kernel<<<1, 256, 0, stream>>>(part, off);
    scan3_kernel<<<SCAN_NBLK, 256, 0, stream>>>(deg, part, off);
    scatter_kernel<<<(ETOT + 255) / 256, 256, 0, stream>>>(ei, off, deg, esrc);

    convw_kernel<<<(IN_C * 256 + 255) / 256, 256, 0, stream>>>(W1, W1th, W1tl, IN_C);
    convw_kernel<<<(F1 * 256 + 255) / 256, 256, 0, stream>>>(W2, W2th, W2tl, F1);

    const int GB = (N_NODES + 63) / 64;
    // layer 1 (gemm writes bf16 h + alpha_src/dst; agg gathers bf16, emits split bf16)
    gemm_mfma<true><<<GB, 256, 0, stream>>>(x, nullptr, nullptr, W1th, W1tl,
                                            as1, ad1, bufHb, asrc, adst, N_NODES, IN_C);
    agg_kernel<1><<<N_NODES, 64, 0, stream>>>(bufHb, asrc, adst, off, esrc, b1,
                                              nullptr, oh, olsp);

    // layer 2
    gemm_mfma<false><<<GB, 256, 0, stream>>>(nullptr, oh, olsp, W2th, W2tl,
                                             as2, ad2, bufHb, asrc, adst, N_NODES, F1);
    agg_kernel<2><<<N_NODES, 64, 0, stream>>>(bufHb, asrc, adst, off, esrc, b2,
                                              bufO, nullptr, nullptr);

    // pool + MLP
    pool2_kernel<<<NB, 256, 0, stream>>>(bufO, bat, pooled);
    mlp_kernel<<<1, 256, 0, stream>>>(pooled, Wm1, bm1, Wm2, bm2, out);
}

// Round 7
// 376.781 us; speedup vs baseline: 1.0309x; 1.0309x over previous
//
#include <hip/hip_runtime.h>
#include <hip/hip_bf16.h>

#define N_NODES 50000
#define N_EDGES 800000
#define ETOT    (N_EDGES + N_NODES)
#define NB      64
#define IN_C    128
#define HID     64
#define HEADS   4
#define F1      (HEADS * HID)   /* 256 */
#define NEG     0.2f
#define SCAN_NBLK ((N_NODES + 255) / 256)   /* 196 */

typedef __attribute__((ext_vector_type(8))) short  short8v;
typedef __attribute__((ext_vector_type(4))) float  float4v;

__device__ __forceinline__ float lrelu(float x) { return x >= 0.f ? x : NEG * x; }

// round-to-nearest-even f32 -> bf16 bits
__device__ __forceinline__ unsigned short f2bf(float f) {
    unsigned u = __float_as_uint(f);
    u += 0x7FFFu + ((u >> 16) & 1u);
    return (unsigned short)(u >> 16);
}
__device__ __forceinline__ float bf2f(unsigned short h) {
    return __uint_as_float(((unsigned)h) << 16);
}

// ---------------- CSR build ----------------
__global__ void deg_kernel(const int* __restrict__ ei, int* __restrict__ deg) {
    int e = blockIdx.x * 256 + threadIdx.x;
    if (e >= ETOT) return;
    int d = (e < N_EDGES) ? ei[N_EDGES + e] : (e - N_EDGES);
    atomicAdd(&deg[d], 1);
}

// 3-phase grid-wide exclusive scan of deg[N_NODES] -> off[N_NODES+1]
__global__ void scan1_kernel(const int* __restrict__ deg, int* __restrict__ part) {
    __shared__ int sh[256];
    int t = threadIdx.x;
    int i = blockIdx.x * 256 + t;
    sh[t] = (i < N_NODES) ? deg[i] : 0;
    __syncthreads();
    #pragma unroll
    for (int o = 128; o; o >>= 1) {
        if (t < o) sh[t] += sh[t + o];
        __syncthreads();
    }
    if (t == 0) part[blockIdx.x] = sh[0];
}

__global__ void scan2_kernel(int* __restrict__ part, int* __restrict__ off) {
    __shared__ int sh[256];
    int t = threadIdx.x;
    int v = (t < SCAN_NBLK) ? part[t] : 0;
    sh[t] = v;
    __syncthreads();
    #pragma unroll
    for (int o = 1; o < 256; o <<= 1) {
        int u = (t >= o) ? sh[t - o] : 0;
        __syncthreads();
        sh[t] += u;
        __syncthreads();
    }
    if (t < SCAN_NBLK) part[t] = sh[t] - v;       // exclusive block base
    if (t == 255) off[N_NODES] = sh[255];
}

__global__ void scan3_kernel(int* __restrict__ deg, const int* __restrict__ part,
                             int* __restrict__ off) {
    __shared__ int sh[256];
    int t = threadIdx.x;
    int i = blockIdx.x * 256 + t;
    int v = (i < N_NODES) ? deg[i] : 0;
    sh[t] = v;
    __syncthreads();
    #pragma unroll
    for (int o = 1; o < 256; o <<= 1) {
        int u = (t >= o) ? sh[t - o] : 0;
        __syncthreads();
        sh[t] += u;
        __syncthreads();
    }
    if (i < N_NODES) {
        off[i] = part[blockIdx.x] + sh[t] - v;
        deg[i] = 0;                                // reuse as cursor
    }
}

__global__ void scatter_kernel(const int* __restrict__ ei, const int* __restrict__ off,
                               int* __restrict__ cursor, int* __restrict__ esrc) {
    int e = blockIdx.x * 256 + threadIdx.x;
    if (e >= ETOT) return;
    int s, d;
    if (e < N_EDGES) { s = ei[e]; d = ei[N_EDGES + e]; }
    else             { s = d = e - N_EDGES; }
    int pos = off[d] + atomicAdd(&cursor[d], 1);
    esrc[pos] = s;
}

// ---------------- both W [K][256] f32 -> transposed split bf16 Wt[256][K] hi/lo ----------------
__global__ void convw2_kernel(const float* __restrict__ W1,
                              unsigned short* __restrict__ W1h, unsigned short* __restrict__ W1l,
                              const float* __restrict__ W2,
                              unsigned short* __restrict__ W2h, unsigned short* __restrict__ W2l) {
    int i = blockIdx.x * 256 + threadIdx.x;
    const int N1 = IN_C * 256;
    if (i < N1) {
        int k = i >> 8, n = i & 255;
        float v = W1[i];
        unsigned short h = f2bf(v);
        W1h[n * IN_C + k] = h;
        W1l[n * IN_C + k] = f2bf(v - bf2f(h));
    } else {
        int j = i - N1;
        if (j >= F1 * 256) return;
        int k = j >> 8, n = j & 255;
        float v = W2[j];
        unsigned short h = f2bf(v);
        W2h[n * F1 + k] = h;
        W2l[n * F1 + k] = f2bf(v - bf2f(h));
    }
}

// ---------------- 2-product bf16 MFMA GEMM + fused alpha + bf16 output ----------------
// C[M,256] = A[M,K] @ W[K,256];  A in plain bf16, W split hi/lo (correlated error kept small).
// Writes Cb (bf16) and per-node alpha_src/alpha_dst. Wave w owns head w's 64 columns.
template <bool SPLIT_A>
__global__ __launch_bounds__(256) void gemm_mfma(const float* __restrict__ Af32,
                                                 const unsigned short* __restrict__ Abg,
                                                 const unsigned short* __restrict__ Wth,
                                                 const unsigned short* __restrict__ Wtl,
                                                 const float* __restrict__ a_s,
                                                 const float* __restrict__ a_d,
                                                 unsigned short* __restrict__ Cb,
                                                 float* __restrict__ asrcO,
                                                 float* __restrict__ adstO,
                                                 int M, int K) {
    __shared__ unsigned short Ab[64][40];                // 32 + 8 pad (80B stride, conflict-free)
    __shared__ unsigned short Bh[256][40], Bl[256][40];
    int t  = threadIdx.x;
    int m0 = blockIdx.x * 64;
    int w  = t >> 6, l = t & 63;
    int lr = l & 15, lk = (l >> 4) * 8;

    float asv[4], adv[4];
    #pragma unroll
    for (int nf = 0; nf < 4; ++nf) {
        asv[nf] = a_s[w * 64 + nf * 16 + lr];
        adv[nf] = a_d[w * 64 + nf * 16 + lr];
    }

    float4v acc[4][4];
    #pragma unroll
    for (int mf = 0; mf < 4; ++mf)
        #pragma unroll
        for (int nf = 0; nf < 4; ++nf)
            acc[mf][nf] = (float4v){0.f, 0.f, 0.f, 0.f};

    for (int k0 = 0; k0 < K; k0 += 32) {
        if (SPLIT_A) {
            #pragma unroll
            for (int p = 0; p < 2; ++p) {
                int idx = t + p * 256;
                int r = idx >> 3, c4 = (idx & 7) * 4;
                int gr = m0 + r;
                float4 v = make_float4(0.f, 0.f, 0.f, 0.f);
                if (gr < M) v = *(const float4*)&Af32[(size_t)gr * K + k0 + c4];
                ushort4 hi;
                hi.x = f2bf(v.x); hi.y = f2bf(v.y); hi.z = f2bf(v.z); hi.w = f2bf(v.w);
                *(ushort4*)&Ab[r][c4] = hi;
            }
        } else {
            int r = t >> 2, c8 = (t & 3) * 8;
            int gr = m0 + r;
            short8v vh = {0,0,0,0,0,0,0,0};
            if (gr < M) vh = *(const short8v*)&Abg[(size_t)gr * K + k0 + c8];
            *(short8v*)&Ab[r][c8] = vh;
        }
        #pragma unroll
        for (int p = 0; p < 4; ++p) {
            int idx = t + p * 256;
            int r = idx >> 2, c8 = (idx & 3) * 8;
            short8v vh = *(const short8v*)&Wth[(size_t)r * K + k0 + c8];
            short8v vl = *(const short8v*)&Wtl[(size_t)r * K + k0 + c8];
            *(short8v*)&Bh[r][c8] = vh;
            *(short8v*)&Bl[r][c8] = vl;
        }
        __syncthreads();

        short8v a_f[4], b_hf[4], b_lf[4];
        #pragma unroll
        for (int mf = 0; mf < 4; ++mf)
            a_f[mf] = *(short8v*)&Ab[mf * 16 + lr][lk];
        #pragma unroll
        for (int nf = 0; nf < 4; ++nf) {
            b_hf[nf] = *(short8v*)&Bh[w * 64 + nf * 16 + lr][lk];
            b_lf[nf] = *(short8v*)&Bl[w * 64 + nf * 16 + lr][lk];
        }
        #pragma unroll
        for (int mf = 0; mf < 4; ++mf)
            #pragma unroll
            for (int nf = 0; nf < 4; ++nf) {
                acc[mf][nf] = __builtin_amdgcn_mfma_f32_16x16x32_bf16(a_f[mf], b_hf[nf], acc[mf][nf], 0, 0, 0);
                acc[mf][nf] = __builtin_amdgcn_mfma_f32_16x16x32_bf16(a_f[mf], b_lf[nf], acc[mf][nf], 0, 0, 0);
            }
        __syncthreads();
    }

    // ---- fused alpha: per-row dot with a_s/a_d (head w), 16-lane reduce ----
    #pragma unroll
    for (int mf = 0; mf < 4; ++mf)
        #pragma unroll
        for (int r = 0; r < 4; ++r) {
            float ps = acc[mf][0][r] * asv[0] + acc[mf][1][r] * asv[1]
                     + acc[mf][2][r] * asv[2] + acc[mf][3][r] * asv[3];
            float pd = acc[mf][0][r] * adv[0] + acc[mf][1][r] * adv[1]
                     + acc[mf][2][r] * adv[2] + acc[mf][3][r] * adv[3];
            #pragma unroll
            for (int o = 8; o; o >>= 1) {
                ps += __shfl_xor(ps, o);
                pd += __shfl_xor(pd, o);
            }
            int gr = m0 + mf * 16 + (l >> 4) * 4 + r;
            if (lr == 0 && gr < M) {
                asrcO[gr * 4 + w] = ps;
                adstO[gr * 4 + w] = pd;
            }
        }

    // ---- bf16 C write (gather source for agg) ----
    #pragma unroll
    for (int mf = 0; mf < 4; ++mf)
        #pragma unroll
        for (int nf = 0; nf < 4; ++nf)
            #pragma unroll
            for (int r = 0; r < 4; ++r) {
                int gr = m0 + mf * 16 + (l >> 4) * 4 + r;
                if (gr < M) Cb[(size_t)gr * F1 + w * 64 + nf * 16 + lr] = f2bf(acc[mf][nf][r]);
            }
}

// ---------------- fused segment softmax + aggregation (one wave per dst node) ----------------
// Lane owns channels lane*4..lane*4+3 (all in head lane>>4): ONE ushort4 gather per edge.
// LAYER 1: out = bf16 relu(agg + bias) (A-input of gemm2); LAYER 2: f32 head-mean + bias.
template <int LAYER>
__global__ void agg_kernel(const unsigned short* __restrict__ hb,
                           const float* __restrict__ asrc,
                           const float* __restrict__ adst,
                           const int* __restrict__ off,
                           const int* __restrict__ esrc,
                           const float* __restrict__ bias,
                           float* __restrict__ outF,
                           unsigned short* __restrict__ oh) {
    __shared__ int   ssh[64];
    __shared__ float cf[64][4];
    int d    = blockIdx.x;
    int lane = threadIdx.x;  // 64 = 1 wave
    int w    = lane >> 4;    // this lane's head
    int e0 = off[d], e1 = off[d + 1];
    float4 ad = *(const float4*)(adst + (size_t)d * 4);
    float den = 0.f;
    float a0 = 0.f, a1 = 0.f, a2 = 0.f, a3 = 0.f;

    for (int base = e0; base < e1; base += 64) {
        int cnt = min(64, e1 - base);
        if (lane < cnt) {
            int s = esrc[base + lane];
            ssh[lane] = s;
            float4 as = *(const float4*)(asrc + (size_t)s * 4);
            cf[lane][0] = __expf(lrelu(as.x + ad.x));
            cf[lane][1] = __expf(lrelu(as.y + ad.y));
            cf[lane][2] = __expf(lrelu(as.z + ad.z));
            cf[lane][3] = __expf(lrelu(as.w + ad.w));
        }
        __syncthreads();
        #pragma unroll 4
        for (int i = 0; i < cnt; ++i) {
            int s = ssh[i];
            float c = cf[i][w];                       // LDS broadcast within head group
            ushort4 hv = *(const ushort4*)&hb[(size_t)s * F1 + lane * 4];
            den += c;
            a0 += c * bf2f(hv.x);
            a1 += c * bf2f(hv.y);
            a2 += c * bf2f(hv.z);
            a3 += c * bf2f(hv.w);
        }
        __syncthreads();
    }

    float r = 1.f / fmaxf(den, 1e-16f);
    if (LAYER == 1) {
        ushort4 hi;
        hi.x = f2bf(fmaxf(a0 * r + bias[lane * 4 + 0], 0.f));
        hi.y = f2bf(fmaxf(a1 * r + bias[lane * 4 + 1], 0.f));
        hi.z = f2bf(fmaxf(a2 * r + bias[lane * 4 + 2], 0.f));
        hi.w = f2bf(fmaxf(a3 * r + bias[lane * 4 + 3], 0.f));
        *(ushort4*)&oh[(size_t)d * F1 + lane * 4] = hi;
    } else {
        float v0 = a0 * r, v1 = a1 * r, v2 = a2 * r, v3 = a3 * r;
        // head-mean: lanes {L, L^16, L^32, L^48} hold same hid for heads 0..3
        v0 += __shfl_xor(v0, 16); v0 += __shfl_xor(v0, 32);
        v1 += __shfl_xor(v1, 16); v1 += __shfl_xor(v1, 32);
        v2 += __shfl_xor(v2, 16); v2 += __shfl_xor(v2, 32);
        v3 += __shfl_xor(v3, 16); v3 += __shfl_xor(v3, 32);
        if (lane < 16) {
            float4 o;
            o.x = 0.25f * v0 + bias[lane * 4 + 0];
            o.y = 0.25f * v1 + bias[lane * 4 + 1];
            o.z = 0.25f * v2 + bias[lane * 4 + 2];
            o.w = 0.25f * v3 + bias[lane * 4 + 3];
            *(float4*)&outF[(size_t)d * HID + lane * 4] = o;
        }
    }
}

// ---------------- global mean pool: one block per graph, batch is sorted ----------------
__device__ __forceinline__ int lowerb(const int* __restrict__ a, int n, int v) {
    int lo = 0, hi = n;
    while (lo < hi) { int m = (lo + hi) >> 1; if (a[m] < v) lo = m + 1; else hi = m; }
    return lo;
}

__global__ void pool2_kernel(const float* __restrict__ h2,
                             const int* __restrict__ batch,
                             float* __restrict__ pooled) {
    __shared__ float sh[4][HID];
    int b = blockIdx.x;
    int t = threadIdx.x, w = t >> 6, c = t & 63;
    int lo = lowerb(batch, N_NODES, b);
    int hi = lowerb(batch, N_NODES, b + 1);
    float s = 0.f;
    for (int n = lo + w; n < hi; n += 4) s += h2[(size_t)n * HID + c];
    sh[w][c] = s;
    __syncthreads();
    if (w == 0) {
        float tot = sh[0][c] + sh[1][c] + sh[2][c] + sh[3][c];
        pooled[b * HID + c] = tot / fmaxf((float)(hi - lo), 1.f);
    }
}

// ---------------- graph MLP ----------------
__global__ void mlp_kernel(const float* __restrict__ pooled,
                           const float* __restrict__ Wm1, const float* __restrict__ bm1,
                           const float* __restrict__ Wm2, const float* __restrict__ bm2,
                           float* __restrict__ out) {
    __shared__ float P[NB][HID];
    __shared__ float Hh[NB][HID];
    int t = threadIdx.x;
    for (int i = t; i < NB * HID; i += 256) P[i / HID][i % HID] = pooled[i];
    __syncthreads();
    for (int i = t; i < NB * HID; i += 256) {
        int b = i / HID, c = i % HID;
        float s = bm1[c];
        for (int k = 0; k < HID; ++k) s += P[b][k] * Wm1[k * HID + c];
        Hh[b][c] = fmaxf(s, 0.f);
    }
    __syncthreads();
    if (t < NB) {
        float s = bm2[0];
        for (int k = 0; k < HID; ++k) s += Hh[t][k] * Wm2[k];
        out[t] = s;
    }
}

extern "C" void kernel_launch(void* const* d_in, const int* in_sizes, int n_in,
                              void* d_out, int out_size, void* d_ws, size_t ws_size,
                              hipStream_t stream) {
    const float* x   = (const float*)d_in[0];
    const int*   ei  = (const int*)d_in[1];
    const int*   bat = (const int*)d_in[2];
    const float* W1  = (const float*)d_in[3];
    const float* as1 = (const float*)d_in[4];
    const float* ad1 = (const float*)d_in[5];
    const float* b1  = (const float*)d_in[6];
    const float* W2  = (const float*)d_in[7];
    const float* as2 = (const float*)d_in[8];
    const float* ad2 = (const float*)d_in[9];
    const float* b2  = (const float*)d_in[10];
    const float* Wm1 = (const float*)d_in[11];
    const float* bm1 = (const float*)d_in[12];
    const float* Wm2 = (const float*)d_in[13];
    const float* bm2 = (const float*)d_in[14];
    float* out = (float*)d_out;

    char* ws = (char*)d_ws;
    size_t cursor = 0;
    auto alloc = [&](size_t bytes) {
        void* p = ws + cursor;
        cursor += (bytes + 511) & ~(size_t)511;
        return p;
    };
    int*   deg    = (int*)alloc((size_t)N_NODES * 4);
    int*   off    = (int*)alloc((size_t)(N_NODES + 1) * 4);
    int*   part   = (int*)alloc((size_t)SCAN_NBLK * 4);
    int*   esrc   = (int*)alloc((size_t)ETOT * 4);
    unsigned short* bufHb = (unsigned short*)alloc((size_t)N_NODES * F1 * 2);  // gemm bf16 out
    // union region: oh (agg1 bf16 out) / bufO (agg2 f32 out) alias
    char*  U      = (char*)alloc((size_t)N_NODES * F1 * 4);
    unsigned short* oh = (unsigned short*)U;
    float* bufO   = (float*)U;
    float* asrc   = (float*)alloc((size_t)N_NODES * HEADS * 4);
    float* adst   = (float*)alloc((size_t)N_NODES * HEADS * 4);
    float* pooled = (float*)alloc((size_t)NB * HID * 4);
    unsigned short* W1th = (unsigned short*)alloc((size_t)256 * IN_C * 2);
    unsigned short* W1tl = (unsigned short*)alloc((size_t)256 * IN_C * 2);
    unsigned short* W2th = (unsigned short*)alloc((size_t)256 * F1 * 2);
    unsigned short* W2tl = (unsigned short*)alloc((size_t)256 * F1 * 2);

    hipMemsetAsync(deg, 0, (size_t)N_NODES * 4, stream);

    deg_kernel<<<(ETOT + 255) / 256, 256, 0, stream>>>(ei, deg);
    scan1_kernel<<<SCAN_NBLK, 256, 0, stream>>>(deg, part);
    scan2_kernel<<<1, 256, 0, stream>>>(part, off);
    scan3_kernel<<<SCAN_NBLK, 256, 0, stream>>>(deg, part, off);
    scatter_kernel<<<(ETOT + 255) / 256, 256, 0, stream>>>(ei, off, deg, esrc);

    convw2_kernel<<<((IN_C + F1) * 256 + 255) / 256, 256, 0, stream>>>(
        W1, W1th, W1tl, W2, W2th, W2tl);

    const int GB = (N_NODES + 63) / 64;
    // layer 1 (gemm writes bf16 h + alpha_src/dst; agg gathers bf16, emits bf16)
    gemm_mfma<true><<<GB, 256, 0, stream>>>(x, nullptr, W1th, W1tl,
                                            as1, ad1, bufHb, asrc, adst, N_NODES, IN_C);
    agg_kernel<1><<<N_NODES, 64, 0, stream>>>(bufHb, asrc, adst, off, esrc, b1,
                                              nullptr, oh);

    // layer 2
    gemm_mfma<false><<<GB, 256, 0, stream>>>(nullptr, oh, W2th, W2tl,
                                             as2, ad2, bufHb, asrc, adst, N_NODES, F1);
    agg_kernel<2><<<N_NODES, 64, 0, stream>>>(bufHb, asrc, adst, off, esrc, b2,
                                              bufO, nullptr);

    // pool + MLP
    pool2_kernel<<<NB, 256, 0, stream>>>(bufO, bat, pooled);
    mlp_kernel<<<1, 256, 0, stream>>>(pooled, Wm1, bm1, Wm2, bm2, out);
}

// Round 8
// 344.114 us; speedup vs baseline: 1.1287x; 1.0949x over previous
//
#include <hip/hip_runtime.h>
#include <hip/hip_bf16.h>

#define N_NODES 50000
#define N_EDGES 800000
#define ETOT    (N_EDGES + N_NODES)
#define NB      64
#define IN_C    128
#define HID     64
#define HEADS   4
#define F1      (HEADS * HID)   /* 256 */
#define NEG     0.2f
#define SCAN_NBLK ((N_NODES + 255) / 256)   /* 196 */

typedef __attribute__((ext_vector_type(8))) short  short8v;
typedef __attribute__((ext_vector_type(4))) float  float4v;

__device__ __forceinline__ float lrelu(float x) { return x >= 0.f ? x : NEG * x; }

// round-to-nearest-even f32 -> bf16 bits
__device__ __forceinline__ unsigned short f2bf(float f) {
    unsigned u = __float_as_uint(f);
    u += 0x7FFFu + ((u >> 16) & 1u);
    return (unsigned short)(u >> 16);
}
__device__ __forceinline__ float bf2f(unsigned short h) {
    return __uint_as_float(((unsigned)h) << 16);
}

// ---------------- CSR build ----------------
__global__ void deg_kernel(const int* __restrict__ ei, int* __restrict__ deg) {
    int e = blockIdx.x * 256 + threadIdx.x;
    if (e >= ETOT) return;
    int d = (e < N_EDGES) ? ei[N_EDGES + e] : (e - N_EDGES);
    atomicAdd(&deg[d], 1);
}

// 3-phase grid-wide exclusive scan of deg[N_NODES] -> off[N_NODES+1]
__global__ void scan1_kernel(const int* __restrict__ deg, int* __restrict__ part) {
    __shared__ int sh[256];
    int t = threadIdx.x;
    int i = blockIdx.x * 256 + t;
    sh[t] = (i < N_NODES) ? deg[i] : 0;
    __syncthreads();
    #pragma unroll
    for (int o = 128; o; o >>= 1) {
        if (t < o) sh[t] += sh[t + o];
        __syncthreads();
    }
    if (t == 0) part[blockIdx.x] = sh[0];
}

__global__ void scan2_kernel(int* __restrict__ part, int* __restrict__ off) {
    __shared__ int sh[256];
    int t = threadIdx.x;
    int v = (t < SCAN_NBLK) ? part[t] : 0;
    sh[t] = v;
    __syncthreads();
    #pragma unroll
    for (int o = 1; o < 256; o <<= 1) {
        int u = (t >= o) ? sh[t - o] : 0;
        __syncthreads();
        sh[t] += u;
        __syncthreads();
    }
    if (t < SCAN_NBLK) part[t] = sh[t] - v;       // exclusive block base
    if (t == 255) off[N_NODES] = sh[255];
}

__global__ void scan3_kernel(int* __restrict__ deg, const int* __restrict__ part,
                             int* __restrict__ off) {
    __shared__ int sh[256];
    int t = threadIdx.x;
    int i = blockIdx.x * 256 + t;
    int v = (i < N_NODES) ? deg[i] : 0;
    sh[t] = v;
    __syncthreads();
    #pragma unroll
    for (int o = 1; o < 256; o <<= 1) {
        int u = (t >= o) ? sh[t - o] : 0;
        __syncthreads();
        sh[t] += u;
        __syncthreads();
    }
    if (i < N_NODES) {
        off[i] = part[blockIdx.x] + sh[t] - v;
        deg[i] = 0;                                // reuse as cursor
    }
}

__global__ void scatter_kernel(const int* __restrict__ ei, const int* __restrict__ off,
                               int* __restrict__ cursor, int* __restrict__ esrc) {
    int e = blockIdx.x * 256 + threadIdx.x;
    if (e >= ETOT) return;
    int s, d;
    if (e < N_EDGES) { s = ei[e]; d = ei[N_EDGES + e]; }
    else             { s = d = e - N_EDGES; }
    int pos = off[d] + atomicAdd(&cursor[d], 1);
    esrc[pos] = s;
}

// ---------------- both W [K][256] f32 -> transposed split bf16 Wt[256][K] hi/lo ----------------
__global__ void convw2_kernel(const float* __restrict__ W1,
                              unsigned short* __restrict__ W1h, unsigned short* __restrict__ W1l,
                              const float* __restrict__ W2,
                              unsigned short* __restrict__ W2h, unsigned short* __restrict__ W2l) {
    int i = blockIdx.x * 256 + threadIdx.x;
    const int N1 = IN_C * 256;
    if (i < N1) {
        int k = i >> 8, n = i & 255;
        float v = W1[i];
        unsigned short h = f2bf(v);
        W1h[n * IN_C + k] = h;
        W1l[n * IN_C + k] = f2bf(v - bf2f(h));
    } else {
        int j = i - N1;
        if (j >= F1 * 256) return;
        int k = j >> 8, n = j & 255;
        float v = W2[j];
        unsigned short h = f2bf(v);
        W2h[n * F1 + k] = h;
        W2l[n * F1 + k] = f2bf(v - bf2f(h));
    }
}

// ---------------- 2-product bf16 MFMA GEMM + fused alpha + bf16 output ----------------
// C[M,256] = A[M,K] @ W[K,256];  A in plain bf16, W split hi/lo (correlated error kept small).
// Writes Cb (bf16) and per-node alpha_src/alpha_dst. Wave w owns head w's 64 columns.
template <bool SPLIT_A>
__global__ __launch_bounds__(256) void gemm_mfma(const float* __restrict__ Af32,
                                                 const unsigned short* __restrict__ Abg,
                                                 const unsigned short* __restrict__ Wth,
                                                 const unsigned short* __restrict__ Wtl,
                                                 const float* __restrict__ a_s,
                                                 const float* __restrict__ a_d,
                                                 unsigned short* __restrict__ Cb,
                                                 float* __restrict__ asrcO,
                                                 float* __restrict__ adstO,
                                                 int M, int K) {
    __shared__ unsigned short Ab[64][40];                // 32 + 8 pad (80B stride, conflict-free)
    __shared__ unsigned short Bh[256][40], Bl[256][40];
    int t  = threadIdx.x;
    int m0 = blockIdx.x * 64;
    int w  = t >> 6, l = t & 63;
    int lr = l & 15, lk = (l >> 4) * 8;

    float asv[4], adv[4];
    #pragma unroll
    for (int nf = 0; nf < 4; ++nf) {
        asv[nf] = a_s[w * 64 + nf * 16 + lr];
        adv[nf] = a_d[w * 64 + nf * 16 + lr];
    }

    float4v acc[4][4];
    #pragma unroll
    for (int mf = 0; mf < 4; ++mf)
        #pragma unroll
        for (int nf = 0; nf < 4; ++nf)
            acc[mf][nf] = (float4v){0.f, 0.f, 0.f, 0.f};

    for (int k0 = 0; k0 < K; k0 += 32) {
        if (SPLIT_A) {
            #pragma unroll
            for (int p = 0; p < 2; ++p) {
                int idx = t + p * 256;
                int r = idx >> 3, c4 = (idx & 7) * 4;
                int gr = m0 + r;
                float4 v = make_float4(0.f, 0.f, 0.f, 0.f);
                if (gr < M) v = *(const float4*)&Af32[(size_t)gr * K + k0 + c4];
                ushort4 hi;
                hi.x = f2bf(v.x); hi.y = f2bf(v.y); hi.z = f2bf(v.z); hi.w = f2bf(v.w);
                *(ushort4*)&Ab[r][c4] = hi;
            }
        } else {
            int r = t >> 2, c8 = (t & 3) * 8;
            int gr = m0 + r;
            short8v vh = {0,0,0,0,0,0,0,0};
            if (gr < M) vh = *(const short8v*)&Abg[(size_t)gr * K + k0 + c8];
            *(short8v*)&Ab[r][c8] = vh;
        }
        #pragma unroll
        for (int p = 0; p < 4; ++p) {
            int idx = t + p * 256;
            int r = idx >> 2, c8 = (idx & 3) * 8;
            short8v vh = *(const short8v*)&Wth[(size_t)r * K + k0 + c8];
            short8v vl = *(const short8v*)&Wtl[(size_t)r * K + k0 + c8];
            *(short8v*)&Bh[r][c8] = vh;
            *(short8v*)&Bl[r][c8] = vl;
        }
        __syncthreads();

        short8v a_f[4], b_hf[4], b_lf[4];
        #pragma unroll
        for (int mf = 0; mf < 4; ++mf)
            a_f[mf] = *(short8v*)&Ab[mf * 16 + lr][lk];
        #pragma unroll
        for (int nf = 0; nf < 4; ++nf) {
            b_hf[nf] = *(short8v*)&Bh[w * 64 + nf * 16 + lr][lk];
            b_lf[nf] = *(short8v*)&Bl[w * 64 + nf * 16 + lr][lk];
        }
        #pragma unroll
        for (int mf = 0; mf < 4; ++mf)
            #pragma unroll
            for (int nf = 0; nf < 4; ++nf) {
                acc[mf][nf] = __builtin_amdgcn_mfma_f32_16x16x32_bf16(a_f[mf], b_hf[nf], acc[mf][nf], 0, 0, 0);
                acc[mf][nf] = __builtin_amdgcn_mfma_f32_16x16x32_bf16(a_f[mf], b_lf[nf], acc[mf][nf], 0, 0, 0);
            }
        __syncthreads();
    }

    // ---- fused alpha: per-row dot with a_s/a_d (head w), 16-lane reduce ----
    #pragma unroll
    for (int mf = 0; mf < 4; ++mf)
        #pragma unroll
        for (int r = 0; r < 4; ++r) {
            float ps = acc[mf][0][r] * asv[0] + acc[mf][1][r] * asv[1]
                     + acc[mf][2][r] * asv[2] + acc[mf][3][r] * asv[3];
            float pd = acc[mf][0][r] * adv[0] + acc[mf][1][r] * adv[1]
                     + acc[mf][2][r] * adv[2] + acc[mf][3][r] * adv[3];
            #pragma unroll
            for (int o = 8; o; o >>= 1) {
                ps += __shfl_xor(ps, o);
                pd += __shfl_xor(pd, o);
            }
            int gr = m0 + mf * 16 + (l >> 4) * 4 + r;
            if (lr == 0 && gr < M) {
                asrcO[gr * 4 + w] = ps;
                adstO[gr * 4 + w] = pd;
            }
        }

    // ---- bf16 C write (gather source for agg) ----
    #pragma unroll
    for (int mf = 0; mf < 4; ++mf)
        #pragma unroll
        for (int nf = 0; nf < 4; ++nf)
            #pragma unroll
            for (int r = 0; r < 4; ++r) {
                int gr = m0 + mf * 16 + (l >> 4) * 4 + r;
                if (gr < M) Cb[(size_t)gr * F1 + w * 64 + nf * 16 + lr] = f2bf(acc[mf][nf][r]);
            }
}

// ---------------- fused segment softmax + aggregation (one wave per dst node) ----------------
// Lane owns channels lane*4..lane*4+3 (all in head lane>>4): ONE ushort4 gather per edge.
// LAYER 1: out = bf16 relu(agg + bias) (A-input of gemm2); LAYER 2: f32 head-mean + bias.
template <int LAYER>
__global__ void agg_kernel(const unsigned short* __restrict__ hb,
                           const float* __restrict__ asrc,
                           const float* __restrict__ adst,
                           const int* __restrict__ off,
                           const int* __restrict__ esrc,
                           const float* __restrict__ bias,
                           float* __restrict__ outF,
                           unsigned short* __restrict__ oh) {
    __shared__ int   ssh[64];
    __shared__ float cf[64][4];
    int d    = blockIdx.x;
    int lane = threadIdx.x;  // 64 = 1 wave
    int w    = lane >> 4;    // this lane's head
    int e0 = off[d], e1 = off[d + 1];
    float4 ad = *(const float4*)(adst + (size_t)d * 4);
    float den = 0.f;
    float a0 = 0.f, a1 = 0.f, a2 = 0.f, a3 = 0.f;

    for (int base = e0; base < e1; base += 64) {
        int cnt = min(64, e1 - base);
        if (lane < cnt) {
            int s = esrc[base + lane];
            ssh[lane] = s;
            float4 as = *(const float4*)(asrc + (size_t)s * 4);
            cf[lane][0] = __expf(lrelu(as.x + ad.x));
            cf[lane][1] = __expf(lrelu(as.y + ad.y));
            cf[lane][2] = __expf(lrelu(as.z + ad.z));
            cf[lane][3] = __expf(lrelu(as.w + ad.w));
        }
        __syncthreads();
        #pragma unroll 4
        for (int i = 0; i < cnt; ++i) {
            int s = ssh[i];
            float c = cf[i][w];                       // LDS broadcast within head group
            ushort4 hv = *(const ushort4*)&hb[(size_t)s * F1 + lane * 4];
            den += c;
            a0 += c * bf2f(hv.x);
            a1 += c * bf2f(hv.y);
            a2 += c * bf2f(hv.z);
            a3 += c * bf2f(hv.w);
        }
        __syncthreads();
    }

    float r = 1.f / fmaxf(den, 1e-16f);
    if (LAYER == 1) {
        ushort4 hi;
        hi.x = f2bf(fmaxf(a0 * r + bias[lane * 4 + 0], 0.f));
        hi.y = f2bf(fmaxf(a1 * r + bias[lane * 4 + 1], 0.f));
        hi.z = f2bf(fmaxf(a2 * r + bias[lane * 4 + 2], 0.f));
        hi.w = f2bf(fmaxf(a3 * r + bias[lane * 4 + 3], 0.f));
        *(ushort4*)&oh[(size_t)d * F1 + lane * 4] = hi;
    } else {
        float v0 = a0 * r, v1 = a1 * r, v2 = a2 * r, v3 = a3 * r;
        // head-mean: lanes {L, L^16, L^32, L^48} hold same hid for heads 0..3
        v0 += __shfl_xor(v0, 16); v0 += __shfl_xor(v0, 32);
        v1 += __shfl_xor(v1, 16); v1 += __shfl_xor(v1, 32);
        v2 += __shfl_xor(v2, 16); v2 += __shfl_xor(v2, 32);
        v3 += __shfl_xor(v3, 16); v3 += __shfl_xor(v3, 32);
        if (lane < 16) {
            float4 o;
            o.x = 0.25f * v0 + bias[lane * 4 + 0];
            o.y = 0.25f * v1 + bias[lane * 4 + 1];
            o.z = 0.25f * v2 + bias[lane * 4 + 2];
            o.w = 0.25f * v3 + bias[lane * 4 + 3];
            *(float4*)&outF[(size_t)d * HID + lane * 4] = o;
        }
    }
}

// ---------------- fused global mean pool + graph MLP: one block per graph ----------------
__device__ __forceinline__ int lowerb(const int* __restrict__ a, int n, int v) {
    int lo = 0, hi = n;
    while (lo < hi) { int m = (lo + hi) >> 1; if (a[m] < v) lo = m + 1; else hi = m; }
    return lo;
}

__global__ void poolmlp_kernel(const float* __restrict__ h2,
                               const int* __restrict__ batch,
                               const float* __restrict__ Wm1, const float* __restrict__ bm1,
                               const float* __restrict__ Wm2, const float* __restrict__ bm2,
                               float* __restrict__ out) {
    __shared__ float sh[4][HID];
    int b = blockIdx.x;
    int t = threadIdx.x, w = t >> 6, c = t & 63;
    int lo = lowerb(batch, N_NODES, b);
    int hi = lowerb(batch, N_NODES, b + 1);
    float s = 0.f;
    for (int n = lo + w; n < hi; n += 4) s += h2[(size_t)n * HID + c];
    sh[w][c] = s;
    __syncthreads();
    if (w == 0) {
        // pooled mean for this graph, lane c owns channel c
        float inv = 1.f / fmaxf((float)(hi - lo), 1.f);
        float P = (sh[0][c] + sh[1][c] + sh[2][c] + sh[3][c]) * inv;
        sh[0][c] = P;                     // within-wave LDS: ordered by lgkmcnt
        // hidden layer: lane c computes h1[c]; Wm1 row-coalesced, sh[0][k] broadcast
        float s1 = bm1[c];
        #pragma unroll
        for (int k = 0; k < HID; ++k) s1 += sh[0][k] * Wm1[k * HID + c];
        float r = fmaxf(s1, 0.f) * Wm2[c];
        #pragma unroll
        for (int o = 32; o; o >>= 1) r += __shfl_xor(r, o);
        if (c == 0) out[b] = r + bm2[0];
    }
}

extern "C" void kernel_launch(void* const* d_in, const int* in_sizes, int n_in,
                              void* d_out, int out_size, void* d_ws, size_t ws_size,
                              hipStream_t stream) {
    const float* x   = (const float*)d_in[0];
    const int*   ei  = (const int*)d_in[1];
    const int*   bat = (const int*)d_in[2];
    const float* W1  = (const float*)d_in[3];
    const float* as1 = (const float*)d_in[4];
    const float* ad1 = (const float*)d_in[5];
    const float* b1  = (const float*)d_in[6];
    const float* W2  = (const float*)d_in[7];
    const float* as2 = (const float*)d_in[8];
    const float* ad2 = (const float*)d_in[9];
    const float* b2  = (const float*)d_in[10];
    const float* Wm1 = (const float*)d_in[11];
    const float* bm1 = (const float*)d_in[12];
    const float* Wm2 = (const float*)d_in[13];
    const float* bm2 = (const float*)d_in[14];
    float* out = (float*)d_out;

    char* ws = (char*)d_ws;
    size_t cursor = 0;
    auto alloc = [&](size_t bytes) {
        void* p = ws + cursor;
        cursor += (bytes + 511) & ~(size_t)511;
        return p;
    };
    int*   deg    = (int*)alloc((size_t)N_NODES * 4);
    int*   off    = (int*)alloc((size_t)(N_NODES + 1) * 4);
    int*   part   = (int*)alloc((size_t)SCAN_NBLK * 4);
    int*   esrc   = (int*)alloc((size_t)ETOT * 4);
    unsigned short* bufHb = (unsigned short*)alloc((size_t)N_NODES * F1 * 2);  // gemm bf16 out
    // union region: oh (agg1 bf16 out) / bufO (agg2 f32 out) alias
    char*  U      = (char*)alloc((size_t)N_NODES * F1 * 4);
    unsigned short* oh = (unsigned short*)U;
    float* bufO   = (float*)U;
    float* asrc   = (float*)alloc((size_t)N_NODES * HEADS * 4);
    float* adst   = (float*)alloc((size_t)N_NODES * HEADS * 4);
    unsigned short* W1th = (unsigned short*)alloc((size_t)256 * IN_C * 2);
    unsigned short* W1tl = (unsigned short*)alloc((size_t)256 * IN_C * 2);
    unsigned short* W2th = (unsigned short*)alloc((size_t)256 * F1 * 2);
    unsigned short* W2tl = (unsigned short*)alloc((size_t)256 * F1 * 2);

    hipMemsetAsync(deg, 0, (size_t)N_NODES * 4, stream);

    deg_kernel<<<(ETOT + 255) / 256, 256, 0, stream>>>(ei, deg);
    scan1_kernel<<<SCAN_NBLK, 256, 0, stream>>>(deg, part);
    scan2_kernel<<<1, 256, 0, stream>>>(part, off);
    scan3_kernel<<<SCAN_NBLK, 256, 0, stream>>>(deg, part, off);
    scatter_kernel<<<(ETOT + 255) / 256, 256, 0, stream>>>(ei, off, deg, esrc);

    convw2_kernel<<<((IN_C + F1) * 256 + 255) / 256, 256, 0, stream>>>(
        W1, W1th, W1tl, W2, W2th, W2tl);

    const int GB = (N_NODES + 63) / 64;
    // layer 1 (gemm writes bf16 h + alpha_src/dst; agg gathers bf16, emits bf16)
    gemm_mfma<true><<<GB, 256, 0, stream>>>(x, nullptr, W1th, W1tl,
                                            as1, ad1, bufHb, asrc, adst, N_NODES, IN_C);
    agg_kernel<1><<<N_NODES, 64, 0, stream>>>(bufHb, asrc, adst, off, esrc, b1,
                                              nullptr, oh);

    // layer 2
    gemm_mfma<false><<<GB, 256, 0, stream>>>(nullptr, oh, W2th, W2tl,
                                             as2, ad2, bufHb, asrc, adst, N_NODES, F1);
    agg_kernel<2><<<N_NODES, 64, 0, stream>>>(bufHb, asrc, adst, off, esrc, b2,
                                              bufO, nullptr);

    // fused pool + MLP (batch sorted -> binary-search ranges; 64 blocks)
    poolmlp_kernel<<<NB, 256, 0, stream>>>(bufO, bat, Wm1, bm1, Wm2, bm2, out);
}

// Round 9
// 343.292 us; speedup vs baseline: 1.1314x; 1.0024x over previous
//
#include <hip/hip_runtime.h>
#include <hip/hip_bf16.h>

#define N_NODES 50000
#define N_EDGES 800000
#define ETOT    (N_EDGES + N_NODES)
#define NB      64
#define IN_C    128
#define HID     64
#define HEADS   4
#define F1      (HEADS * HID)   /* 256 */
#define NEG     0.2f
#define SCAN_NBLK ((N_NODES + 255) / 256)   /* 196 */

typedef __attribute__((ext_vector_type(8))) short  short8v;
typedef __attribute__((ext_vector_type(4))) float  float4v;

__device__ __forceinline__ float lrelu(float x) { return x >= 0.f ? x : NEG * x; }

// round-to-nearest-even f32 -> bf16 bits
__device__ __forceinline__ unsigned short f2bf(float f) {
    unsigned u = __float_as_uint(f);
    u += 0x7FFFu + ((u >> 16) & 1u);
    return (unsigned short)(u >> 16);
}
__device__ __forceinline__ float bf2f(unsigned short h) {
    return __uint_as_float(((unsigned)h) << 16);
}

// ---------------- CSR build ----------------
__global__ void deg_kernel(const int* __restrict__ ei, int* __restrict__ deg) {
    int e = blockIdx.x * 256 + threadIdx.x;
    if (e >= ETOT) return;
    int d = (e < N_EDGES) ? ei[N_EDGES + e] : (e - N_EDGES);
    atomicAdd(&deg[d], 1);
}

// 3-phase grid-wide exclusive scan of deg[N_NODES] -> off[N_NODES+1]
__global__ void scan1_kernel(const int* __restrict__ deg, int* __restrict__ part) {
    __shared__ int sh[256];
    int t = threadIdx.x;
    int i = blockIdx.x * 256 + t;
    sh[t] = (i < N_NODES) ? deg[i] : 0;
    __syncthreads();
    #pragma unroll
    for (int o = 128; o; o >>= 1) {
        if (t < o) sh[t] += sh[t + o];
        __syncthreads();
    }
    if (t == 0) part[blockIdx.x] = sh[0];
}

__global__ void scan2_kernel(int* __restrict__ part, int* __restrict__ off) {
    __shared__ int sh[256];
    int t = threadIdx.x;
    int v = (t < SCAN_NBLK) ? part[t] : 0;
    sh[t] = v;
    __syncthreads();
    #pragma unroll
    for (int o = 1; o < 256; o <<= 1) {
        int u = (t >= o) ? sh[t - o] : 0;
        __syncthreads();
        sh[t] += u;
        __syncthreads();
    }
    if (t < SCAN_NBLK) part[t] = sh[t] - v;       // exclusive block base
    if (t == 255) off[N_NODES] = sh[255];
}

__global__ void scan3_kernel(int* __restrict__ deg, const int* __restrict__ part,
                             int* __restrict__ off) {
    __shared__ int sh[256];
    int t = threadIdx.x;
    int i = blockIdx.x * 256 + t;
    int v = (i < N_NODES) ? deg[i] : 0;
    sh[t] = v;
    __syncthreads();
    #pragma unroll
    for (int o = 1; o < 256; o <<= 1) {
        int u = (t >= o) ? sh[t - o] : 0;
        __syncthreads();
        sh[t] += u;
        __syncthreads();
    }
    if (i < N_NODES) {
        off[i] = part[blockIdx.x] + sh[t] - v;
        deg[i] = 0;                                // reuse as cursor
    }
}

__global__ void scatter_kernel(const int* __restrict__ ei, const int* __restrict__ off,
                               int* __restrict__ cursor, int* __restrict__ esrc) {
    int e = blockIdx.x * 256 + threadIdx.x;
    if (e >= ETOT) return;
    int s, d;
    if (e < N_EDGES) { s = ei[e]; d = ei[N_EDGES + e]; }
    else             { s = d = e - N_EDGES; }
    int pos = off[d] + atomicAdd(&cursor[d], 1);
    esrc[pos] = s;
}

// ---------------- both W [K][256] f32 -> transposed split bf16 Wt[256][K] hi/lo ----------------
__global__ void convw2_kernel(const float* __restrict__ W1,
                              unsigned short* __restrict__ W1h, unsigned short* __restrict__ W1l,
                              const float* __restrict__ W2,
                              unsigned short* __restrict__ W2h, unsigned short* __restrict__ W2l) {
    int i = blockIdx.x * 256 + threadIdx.x;
    const int N1 = IN_C * 256;
    if (i < N1) {
        int k = i >> 8, n = i & 255;
        float v = W1[i];
        unsigned short h = f2bf(v);
        W1h[n * IN_C + k] = h;
        W1l[n * IN_C + k] = f2bf(v - bf2f(h));
    } else {
        int j = i - N1;
        if (j >= F1 * 256) return;
        int k = j >> 8, n = j & 255;
        float v = W2[j];
        unsigned short h = f2bf(v);
        W2h[n * F1 + k] = h;
        W2l[n * F1 + k] = f2bf(v - bf2f(h));
    }
}

// ---------------- 2-product bf16 MFMA GEMM + fused alpha + bf16 output ----------------
// C[M,256] = A[M,K] @ W[K,256];  A in plain bf16, W split hi/lo (correlated error kept small).
// Writes Cb (bf16) and per-node alpha_src/alpha_dst. Wave w owns head w's 64 columns.
template <bool SPLIT_A>
__global__ __launch_bounds__(256) void gemm_mfma(const float* __restrict__ Af32,
                                                 const unsigned short* __restrict__ Abg,
                                                 const unsigned short* __restrict__ Wth,
                                                 const unsigned short* __restrict__ Wtl,
                                                 const float* __restrict__ a_s,
                                                 const float* __restrict__ a_d,
                                                 unsigned short* __restrict__ Cb,
                                                 float* __restrict__ asrcO,
                                                 float* __restrict__ adstO,
                                                 int M, int K) {
    __shared__ unsigned short Ab[64][40];                // 32 + 8 pad (80B stride, conflict-free)
    __shared__ unsigned short Bh[256][40], Bl[256][40];
    int t  = threadIdx.x;
    int m0 = blockIdx.x * 64;
    int w  = t >> 6, l = t & 63;
    int lr = l & 15, lk = (l >> 4) * 8;

    float asv[4], adv[4];
    #pragma unroll
    for (int nf = 0; nf < 4; ++nf) {
        asv[nf] = a_s[w * 64 + nf * 16 + lr];
        adv[nf] = a_d[w * 64 + nf * 16 + lr];
    }

    float4v acc[4][4];
    #pragma unroll
    for (int mf = 0; mf < 4; ++mf)
        #pragma unroll
        for (int nf = 0; nf < 4; ++nf)
            acc[mf][nf] = (float4v){0.f, 0.f, 0.f, 0.f};

    for (int k0 = 0; k0 < K; k0 += 32) {
        if (SPLIT_A) {
            #pragma unroll
            for (int p = 0; p < 2; ++p) {
                int idx = t + p * 256;
                int r = idx >> 3, c4 = (idx & 7) * 4;
                int gr = m0 + r;
                float4 v = make_float4(0.f, 0.f, 0.f, 0.f);
                if (gr < M) v = *(const float4*)&Af32[(size_t)gr * K + k0 + c4];
                ushort4 hi;
                hi.x = f2bf(v.x); hi.y = f2bf(v.y); hi.z = f2bf(v.z); hi.w = f2bf(v.w);
                *(ushort4*)&Ab[r][c4] = hi;
            }
        } else {
            int r = t >> 2, c8 = (t & 3) * 8;
            int gr = m0 + r;
            short8v vh = {0,0,0,0,0,0,0,0};
            if (gr < M) vh = *(const short8v*)&Abg[(size_t)gr * K + k0 + c8];
            *(short8v*)&Ab[r][c8] = vh;
        }
        #pragma unroll
        for (int p = 0; p < 4; ++p) {
            int idx = t + p * 256;
            int r = idx >> 2, c8 = (idx & 3) * 8;
            short8v vh = *(const short8v*)&Wth[(size_t)r * K + k0 + c8];
            short8v vl = *(const short8v*)&Wtl[(size_t)r * K + k0 + c8];
            *(short8v*)&Bh[r][c8] = vh;
            *(short8v*)&Bl[r][c8] = vl;
        }
        __syncthreads();

        short8v a_f[4], b_hf[4], b_lf[4];
        #pragma unroll
        for (int mf = 0; mf < 4; ++mf)
            a_f[mf] = *(short8v*)&Ab[mf * 16 + lr][lk];
        #pragma unroll
        for (int nf = 0; nf < 4; ++nf) {
            b_hf[nf] = *(short8v*)&Bh[w * 64 + nf * 16 + lr][lk];
            b_lf[nf] = *(short8v*)&Bl[w * 64 + nf * 16 + lr][lk];
        }
        #pragma unroll
        for (int mf = 0; mf < 4; ++mf)
            #pragma unroll
            for (int nf = 0; nf < 4; ++nf) {
                acc[mf][nf] = __builtin_amdgcn_mfma_f32_16x16x32_bf16(a_f[mf], b_hf[nf], acc[mf][nf], 0, 0, 0);
                acc[mf][nf] = __builtin_amdgcn_mfma_f32_16x16x32_bf16(a_f[mf], b_lf[nf], acc[mf][nf], 0, 0, 0);
            }
        __syncthreads();
    }

    // ---- fused alpha: per-row dot with a_s/a_d (head w), 16-lane reduce ----
    #pragma unroll
    for (int mf = 0; mf < 4; ++mf)
        #pragma unroll
        for (int r = 0; r < 4; ++r) {
            float ps = acc[mf][0][r] * asv[0] + acc[mf][1][r] * asv[1]
                     + acc[mf][2][r] * asv[2] + acc[mf][3][r] * asv[3];
            float pd = acc[mf][0][r] * adv[0] + acc[mf][1][r] * adv[1]
                     + acc[mf][2][r] * adv[2] + acc[mf][3][r] * adv[3];
            #pragma unroll
            for (int o = 8; o; o >>= 1) {
                ps += __shfl_xor(ps, o);
                pd += __shfl_xor(pd, o);
            }
            int gr = m0 + mf * 16 + (l >> 4) * 4 + r;
            if (lr == 0 && gr < M) {
                asrcO[gr * 4 + w] = ps;
                adstO[gr * 4 + w] = pd;
            }
        }

    // ---- bf16 C write (gather source for agg) ----
    #pragma unroll
    for (int mf = 0; mf < 4; ++mf)
        #pragma unroll
        for (int nf = 0; nf < 4; ++nf)
            #pragma unroll
            for (int r = 0; r < 4; ++r) {
                int gr = m0 + mf * 16 + (l >> 4) * 4 + r;
                if (gr < M) Cb[(size_t)gr * F1 + w * 64 + nf * 16 + lr] = f2bf(acc[mf][nf][r]);
            }
}

// ---------------- fused segment softmax + aggregation (one wave per dst node) ----------------
// Lane owns channels lane*4..lane*4+3 (head lane>>4): ONE ushort4 gather per edge.
// Inner loop explicitly 4-deep batched: 4 outstanding gathers per wave (latency hiding).
// LAYER 1: out = bf16 relu(agg + bias); LAYER 2: f32 head-mean + bias.
template <int LAYER>
__global__ void agg_kernel(const unsigned short* __restrict__ hb,
                           const float* __restrict__ asrc,
                           const float* __restrict__ adst,
                           const int* __restrict__ off,
                           const int* __restrict__ esrc,
                           const float* __restrict__ bias,
                           float* __restrict__ outF,
                           unsigned short* __restrict__ oh) {
    __shared__ int   soff[64];            // precomputed byte offsets s*512
    __shared__ float cf[64][4];
    int d    = blockIdx.x;
    int lane = threadIdx.x;  // 64 = 1 wave
    int w    = lane >> 4;    // this lane's head
    int e0 = off[d], e1 = off[d + 1];
    float4 ad = *(const float4*)(adst + (size_t)d * 4);
    float den = 0.f;
    float a0 = 0.f, a1 = 0.f, a2 = 0.f, a3 = 0.f;
    const char* hbase = (const char*)hb;
    int lb = lane * 8;                    // this lane's byte offset within a row

    for (int base = e0; base < e1; base += 64) {
        int cnt = min(64, e1 - base);
        if (lane < cnt) {
            int s = esrc[base + lane];
            soff[lane] = s * (F1 * 2);
            float4 as = *(const float4*)(asrc + (size_t)s * 4);
            cf[lane][0] = __expf(lrelu(as.x + ad.x));
            cf[lane][1] = __expf(lrelu(as.y + ad.y));
            cf[lane][2] = __expf(lrelu(as.z + ad.z));
            cf[lane][3] = __expf(lrelu(as.w + ad.w));
        }
        __syncthreads();
        int i = 0;
        for (; i + 4 <= cnt; i += 4) {
            int o0 = soff[i], o1 = soff[i + 1], o2 = soff[i + 2], o3 = soff[i + 3];
            ushort4 h0 = *(const ushort4*)(hbase + o0 + lb);
            ushort4 h1 = *(const ushort4*)(hbase + o1 + lb);
            ushort4 h2 = *(const ushort4*)(hbase + o2 + lb);
            ushort4 h3 = *(const ushort4*)(hbase + o3 + lb);
            float c0 = cf[i][w], c1 = cf[i + 1][w], c2 = cf[i + 2][w], c3 = cf[i + 3][w];
            den += (c0 + c1) + (c2 + c3);
            a0 += c0 * bf2f(h0.x) + c1 * bf2f(h1.x) + c2 * bf2f(h2.x) + c3 * bf2f(h3.x);
            a1 += c0 * bf2f(h0.y) + c1 * bf2f(h1.y) + c2 * bf2f(h2.y) + c3 * bf2f(h3.y);
            a2 += c0 * bf2f(h0.z) + c1 * bf2f(h1.z) + c2 * bf2f(h2.z) + c3 * bf2f(h3.z);
            a3 += c0 * bf2f(h0.w) + c1 * bf2f(h1.w) + c2 * bf2f(h2.w) + c3 * bf2f(h3.w);
        }
        for (; i < cnt; ++i) {
            int o = soff[i];
            float c = cf[i][w];
            ushort4 hv = *(const ushort4*)(hbase + o + lb);
            den += c;
            a0 += c * bf2f(hv.x);
            a1 += c * bf2f(hv.y);
            a2 += c * bf2f(hv.z);
            a3 += c * bf2f(hv.w);
        }
        __syncthreads();
    }

    float r = 1.f / fmaxf(den, 1e-16f);
    if (LAYER == 1) {
        ushort4 hi;
        hi.x = f2bf(fmaxf(a0 * r + bias[lane * 4 + 0], 0.f));
        hi.y = f2bf(fmaxf(a1 * r + bias[lane * 4 + 1], 0.f));
        hi.z = f2bf(fmaxf(a2 * r + bias[lane * 4 + 2], 0.f));
        hi.w = f2bf(fmaxf(a3 * r + bias[lane * 4 + 3], 0.f));
        *(ushort4*)&oh[(size_t)d * F1 + lane * 4] = hi;
    } else {
        float v0 = a0 * r, v1 = a1 * r, v2 = a2 * r, v3 = a3 * r;
        // head-mean: lanes {L, L^16, L^32, L^48} hold same hid for heads 0..3
        v0 += __shfl_xor(v0, 16); v0 += __shfl_xor(v0, 32);
        v1 += __shfl_xor(v1, 16); v1 += __shfl_xor(v1, 32);
        v2 += __shfl_xor(v2, 16); v2 += __shfl_xor(v2, 32);
        v3 += __shfl_xor(v3, 16); v3 += __shfl_xor(v3, 32);
        if (lane < 16) {
            float4 o;
            o.x = 0.25f * v0 + bias[lane * 4 + 0];
            o.y = 0.25f * v1 + bias[lane * 4 + 1];
            o.z = 0.25f * v2 + bias[lane * 4 + 2];
            o.w = 0.25f * v3 + bias[lane * 4 + 3];
            *(float4*)&outF[(size_t)d * HID + lane * 4] = o;
        }
    }
}

// ---------------- fused global mean pool + graph MLP: one block per graph ----------------
__device__ __forceinline__ int lowerb(const int* __restrict__ a, int n, int v) {
    int lo = 0, hi = n;
    while (lo < hi) { int m = (lo + hi) >> 1; if (a[m] < v) lo = m + 1; else hi = m; }
    return lo;
}

__global__ void poolmlp_kernel(const float* __restrict__ h2,
                               const int* __restrict__ batch,
                               const float* __restrict__ Wm1, const float* __restrict__ bm1,
                               const float* __restrict__ Wm2, const float* __restrict__ bm2,
                               float* __restrict__ out) {
    __shared__ float sh[4][HID];
    int b = blockIdx.x;
    int t = threadIdx.x, w = t >> 6, c = t & 63;
    int lo = lowerb(batch, N_NODES, b);
    int hi = lowerb(batch, N_NODES, b + 1);
    float s = 0.f;
    for (int n = lo + w; n < hi; n += 4) s += h2[(size_t)n * HID + c];
    sh[w][c] = s;
    __syncthreads();
    if (w == 0) {
        // pooled mean for this graph, lane c owns channel c
        float inv = 1.f / fmaxf((float)(hi - lo), 1.f);
        float P = (sh[0][c] + sh[1][c] + sh[2][c] + sh[3][c]) * inv;
        sh[0][c] = P;                     // within-wave LDS: ordered by lgkmcnt
        // hidden layer: lane c computes h1[c]; Wm1 row-coalesced, sh[0][k] broadcast
        float s1 = bm1[c];
        #pragma unroll
        for (int k = 0; k < HID; ++k) s1 += sh[0][k] * Wm1[k * HID + c];
        float r = fmaxf(s1, 0.f) * Wm2[c];
        #pragma unroll
        for (int o = 32; o; o >>= 1) r += __shfl_xor(r, o);
        if (c == 0) out[b] = r + bm2[0];
    }
}

extern "C" void kernel_launch(void* const* d_in, const int* in_sizes, int n_in,
                              void* d_out, int out_size, void* d_ws, size_t ws_size,
                              hipStream_t stream) {
    const float* x   = (const float*)d_in[0];
    const int*   ei  = (const int*)d_in[1];
    const int*   bat = (const int*)d_in[2];
    const float* W1  = (const float*)d_in[3];
    const float* as1 = (const float*)d_in[4];
    const float* ad1 = (const float*)d_in[5];
    const float* b1  = (const float*)d_in[6];
    const float* W2  = (const float*)d_in[7];
    const float* as2 = (const float*)d_in[8];
    const float* ad2 = (const float*)d_in[9];
    const float* b2  = (const float*)d_in[10];
    const float* Wm1 = (const float*)d_in[11];
    const float* bm1 = (const float*)d_in[12];
    const float* Wm2 = (const float*)d_in[13];
    const float* bm2 = (const float*)d_in[14];
    float* out = (float*)d_out;

    char* ws = (char*)d_ws;
    size_t cursor = 0;
    auto alloc = [&](size_t bytes) {
        void* p = ws + cursor;
        cursor += (bytes + 511) & ~(size_t)511;
        return p;
    };
    int*   deg    = (int*)alloc((size_t)N_NODES * 4);
    int*   off    = (int*)alloc((size_t)(N_NODES + 1) * 4);
    int*   part   = (int*)alloc((size_t)SCAN_NBLK * 4);
    int*   esrc   = (int*)alloc((size_t)ETOT * 4);
    unsigned short* bufHb = (unsigned short*)alloc((size_t)N_NODES * F1 * 2);  // gemm bf16 out
    // union region: oh (agg1 bf16 out) / bufO (agg2 f32 out) alias
    char*  U      = (char*)alloc((size_t)N_NODES * F1 * 4);
    unsigned short* oh = (unsigned short*)U;
    float* bufO   = (float*)U;
    float* asrc   = (float*)alloc((size_t)N_NODES * HEADS * 4);
    float* adst   = (float*)alloc((size_t)N_NODES * HEADS * 4);
    unsigned short* W1th = (unsigned short*)alloc((size_t)256 * IN_C * 2);
    unsigned short* W1tl = (unsigned short*)alloc((size_t)256 * IN_C * 2);
    unsigned short* W2th = (unsigned short*)alloc((size_t)256 * F1 * 2);
    unsigned short* W2tl = (unsigned short*)alloc((size_t)256 * F1 * 2);

    hipMemsetAsync(deg, 0, (size_t)N_NODES * 4, stream);

    deg_kernel<<<(ETOT + 255) / 256, 256, 0, stream>>>(ei, deg);
    scan1_kernel<<<SCAN_NBLK, 256, 0, stream>>>(deg, part);
    scan2_kernel<<<1, 256, 0, stream>>>(part, off);
    scan3_kernel<<<SCAN_NBLK, 256, 0, stream>>>(deg, part, off);
    scatter_kernel<<<(ETOT + 255) / 256, 256, 0, stream>>>(ei, off, deg, esrc);

    convw2_kernel<<<((IN_C + F1) * 256 + 255) / 256, 256, 0, stream>>>(
        W1, W1th, W1tl, W2, W2th, W2tl);

    const int GB = (N_NODES + 63) / 64;
    // layer 1 (gemm writes bf16 h + alpha_src/dst; agg gathers bf16, emits bf16)
    gemm_mfma<true><<<GB, 256, 0, stream>>>(x, nullptr, W1th, W1tl,
                                            as1, ad1, bufHb, asrc, adst, N_NODES, IN_C);
    agg_kernel<1><<<N_NODES, 64, 0, stream>>>(bufHb, asrc, adst, off, esrc, b1,
                                              nullptr, oh);

    // layer 2
    gemm_mfma<false><<<GB, 256, 0, stream>>>(nullptr, oh, W2th, W2tl,
                                             as2, ad2, bufHb, asrc, adst, N_NODES, F1);
    agg_kernel<2><<<N_NODES, 64, 0, stream>>>(bufHb, asrc, adst, off, esrc, b2,
                                              bufO, nullptr);

    // fused pool + MLP (batch sorted -> binary-search ranges; 64 blocks)
    poolmlp_kernel<<<NB, 256, 0, stream>>>(bufO, bat, Wm1, bm1, Wm2, bm2, out);
}